// Round 4
// baseline (83.865 us; speedup 1.0000x reference)
//
#include <hip/hip_runtime.h>
#include <cmath>

typedef __attribute__((ext_vector_type(8))) __bf16 bf16x8;
typedef __attribute__((ext_vector_type(4))) float f32x4;

namespace {
constexpr int GP = 512;
constexpr int WS_Q = 0;
constexpr int WS_K = 524288;
constexpr int WS_V = 1048576;
}

__device__ inline unsigned short f2bf(float x) {
  union { float f; unsigned u; } v; v.f = x;
  unsigned r = v.u + 0x7fff + ((v.u >> 16) & 1);   // RNE
  return (unsigned short)(r >> 16);
}

__device__ inline void cvt8_store(unsigned short* dst, float4 a, float4 b) {
  ushort4 lo, hi;
  lo.x = f2bf(a.x); lo.y = f2bf(a.y); lo.z = f2bf(a.z); lo.w = f2bf(a.w);
  hi.x = f2bf(b.x); hi.y = f2bf(b.y); hi.z = f2bf(b.z); hi.w = f2bf(b.w);
  *(ushort4*)dst = lo; *(ushort4*)(dst + 4) = hi;
}

// ---------------------------------------------------------------------------
// Kernel 1: QKV projection (bf16 MFMA, fp32 inputs converted in staging)
//           + log1p(relu)-lam + tropical linear + scramble-write of q/k/v.
// grid (24,16): blockIdx.x = head-column block (0-7 q, 8-15 k, 16-23 v),
//               blockIdx.y = 64-row block of tokens.
// ---------------------------------------------------------------------------
__global__ __launch_bounds__(256) void k_gemm0t(const float* __restrict__ h,
    const float* __restrict__ Wq, const float* __restrict__ Wkv,
    const float* __restrict__ lam, const float* __restrict__ Wqt,
    const float* __restrict__ Wkt, const float* __restrict__ Wvt,
    float* __restrict__ qkv)
{
  __shared__ unsigned short As[64][72];
  __shared__ unsigned short Bs[64][72];
  __shared__ float Wl[64][65];
  __shared__ float nl[64][68];
  const int tid = threadIdx.x;
  const int bx = blockIdx.x;
  const int r0 = blockIdx.y * 64, c0 = bx * 64;
  const int which = c0 >> 9;            // 0=q,1=k,2=v
  const int hh = bx & 7;                // head
  const float* Wt = (which == 0) ? Wqt : (which == 1) ? Wkt : Wvt;
  #pragma unroll
  for (int q = 0; q < 16; ++q) {        // stage Wt (coalesced)
    int idx = q * 256 + tid;
    Wl[idx >> 6][idx & 63] = Wt[idx];
  }
  const int w = tid >> 6, l = tid & 63;
  const int wr = (w >> 1) * 32, wc = (w & 1) * 32;
  const int srow = tid >> 3, sk8 = (tid & 7) * 8;
  f32x4 acc[2][2] = {};
  for (int kk = 0; kk < 512; kk += 64) {
    __syncthreads();
    #pragma unroll
    for (int q2 = 0; q2 < 2; ++q2) {
      int row = srow + q2 * 32;
      const float* ap = &h[(r0 + row) * 512 + kk + sk8];
      cvt8_store(&As[row][sk8], *(const float4*)ap, *(const float4*)(ap + 4));
      int c = c0 + row;
      const float* wrp = (c < 512) ? (Wq + c * 512) : (Wkv + (c - 512) * 512);
      cvt8_store(&Bs[row][sk8], *(const float4*)&wrp[kk + sk8],
                 *(const float4*)&wrp[kk + sk8 + 4]);
    }
    __syncthreads();
    #pragma unroll
    for (int ks = 0; ks < 2; ++ks) {
      const int kc = ks * 32 + (l >> 4) * 8;
      bf16x8 a0 = *(const bf16x8*)&As[wr +      (l & 15)][kc];
      bf16x8 a1 = *(const bf16x8*)&As[wr + 16 + (l & 15)][kc];
      bf16x8 b0 = *(const bf16x8*)&Bs[wc +      (l & 15)][kc];
      bf16x8 b1 = *(const bf16x8*)&Bs[wc + 16 + (l & 15)][kc];
      acc[0][0] = __builtin_amdgcn_mfma_f32_16x16x32_bf16(a0, b0, acc[0][0], 0, 0, 0);
      acc[0][1] = __builtin_amdgcn_mfma_f32_16x16x32_bf16(a0, b1, acc[0][1], 0, 0, 0);
      acc[1][0] = __builtin_amdgcn_mfma_f32_16x16x32_bf16(a1, b0, acc[1][0], 0, 0, 0);
      acc[1][1] = __builtin_amdgcn_mfma_f32_16x16x32_bf16(a1, b1, acc[1][1], 0, 0, 0);
    }
  }
  // epilogue: norm into LDS nl
  #pragma unroll
  for (int i = 0; i < 2; ++i)
    #pragma unroll
    for (int j = 0; j < 2; ++j)
      #pragma unroll
      for (int r = 0; r < 4; ++r) {
        int rl = wr + i * 16 + (l >> 4) * 4 + r;
        int cl = wc + j * 16 + (l & 15);
        nl[rl][cl] = log1pf(fmaxf(acc[i][j][r], 0.f)) - lam[hh * 64 + cl];
      }
  __syncthreads();
  // tropical linear: out[g][p][d=l] = max_i(nl[row][i] + Wt[d][i])
  float wreg[64];
  #pragma unroll
  for (int i = 0; i < 64; ++i) wreg[i] = Wl[l][i];   // 2-way (free)
  #pragma unroll 2
  for (int it = 0; it < 16; ++it) {
    int lr = w + it * 4;                 // wave-uniform row -> broadcast reads
    float m0 = -INFINITY, m1 = -INFINITY, m2 = -INFINITY, m3 = -INFINITY;
    #pragma unroll
    for (int i = 0; i < 64; i += 4) {
      f32x4 nv = *(const f32x4*)&nl[lr][i];
      m0 = fmaxf(m0, nv[0] + wreg[i]);
      m1 = fmaxf(m1, nv[1] + wreg[i + 1]);
      m2 = fmaxf(m2, nv[2] + wreg[i + 2]);
      m3 = fmaxf(m3, nv[3] + wreg[i + 3]);
    }
    int r = r0 + lr;
    int s = r >> 1, bb = r & 1;
    int g = bb * 8 + (s >> 6);
    int p = ((s & 63) << 3) | hh;
    qkv[which * 524288 + ((g << 9) + p) * 64 + l] =
        fmaxf(fmaxf(m0, m1), fmaxf(m2, m3));
  }
}

// ---------------------------------------------------------------------------
// Kernel 2: tropical attention, c-split 4 ways, fp32 partial ctx out.
// ---------------------------------------------------------------------------
__global__ __launch_bounds__(256) void k_attn(const float* __restrict__ qkv,
    float* __restrict__ ctxp)
{
  const int pt = blockIdx.x;
  const int g  = blockIdx.y;
  const int cs = blockIdx.z;
  const float* qb = qkv + WS_Q + g * GP * 64;
  const float* kb = qkv + WS_K + g * GP * 64;
  const float* vb = qkv + WS_V + g * GP * 64;
  __shared__ float qs[32][64];
  __shared__ float ks[64][64];
  __shared__ float vs[64][64];
  __shared__ float ss[32][68];
  const int tid = threadIdx.x;
  const int tr = tid >> 4, tc = tid & 15;
  const int xb = tc & 7;
  #pragma unroll
  for (int q2 = 0; q2 < 2; ++q2) {
    int row = tr + q2 * 16;
    f32x4 v4 = *(const f32x4*)&qb[(pt * 32 + row) * 64 + tc * 4];
    *(f32x4*)&qs[row][((tc ^ (row & 7))) * 4] = v4;
  }
  float ctx[2][4];
  #pragma unroll
  for (int i = 0; i < 2; ++i)
    #pragma unroll
    for (int j = 0; j < 4; ++j) ctx[i][j] = -INFINITY;

  for (int cc = 0; cc < 2; ++cc) {
    const int c0 = cs * 128 + cc * 64;
    __syncthreads();
    #pragma unroll
    for (int q4 = 0; q4 < 4; ++q4) {
      int row = tr + q4 * 16;
      int sb = (tc ^ (row & 7)) * 4;
      *(f32x4*)&ks[row][sb] = *(const f32x4*)&kb[(c0 + row) * 64 + tc * 4];
      *(f32x4*)&vs[row][sb] = *(const f32x4*)&vb[(c0 + row) * 64 + tc * 4];
    }
    __syncthreads();
    float mx[2][4], mn[2][4];
    #pragma unroll
    for (int i = 0; i < 2; ++i)
      #pragma unroll
      for (int m = 0; m < 4; ++m) { mx[i][m] = -INFINITY; mn[i][m] = INFINITY; }
    const int r0 = tr * 2, r1 = r0 + 1;
    #pragma unroll 2
    for (int b = 0; b < 16; ++b) {
      f32x4 q0 = *(const f32x4*)&qs[r0][(b ^ (r0 & 7)) * 4];
      f32x4 q1 = *(const f32x4*)&qs[r1][(b ^ (r1 & 7)) * 4];
      const int kblk = (b ^ xb) * 4;
      #pragma unroll
      for (int m = 0; m < 4; ++m) {
        f32x4 kv = *(const f32x4*)&ks[tc + m * 16][kblk];
        #pragma unroll
        for (int e = 0; e < 4; ++e) {
          float d0 = q0[e] - kv[e];
          float d1 = q1[e] - kv[e];
          mx[0][m] = fmaxf(mx[0][m], d0); mn[0][m] = fminf(mn[0][m], d0);
          mx[1][m] = fmaxf(mx[1][m], d1); mn[1][m] = fminf(mn[1][m], d1);
        }
      }
    }
    #pragma unroll
    for (int i = 0; i < 2; ++i)
      #pragma unroll
      for (int m = 0; m < 4; ++m)
        ss[tr * 2 + i][tc + m * 16] = mn[i][m] - mx[i][m];
    __syncthreads();
    #pragma unroll 2
    for (int cb = 0; cb < 16; ++cb) {
      f32x4 s0 = *(const f32x4*)&ss[r0][cb * 4];
      f32x4 s1 = *(const f32x4*)&ss[r1][cb * 4];
      #pragma unroll
      for (int e = 0; e < 4; ++e) {
        int c = cb * 4 + e;
        f32x4 vv = *(const f32x4*)&vs[c][(tc ^ (c & 7)) * 4];
        #pragma unroll
        for (int j = 0; j < 4; ++j) {
          ctx[0][j] = fmaxf(ctx[0][j], s0[e] + vv[j]);
          ctx[1][j] = fmaxf(ctx[1][j], s1[e] + vv[j]);
        }
      }
    }
  }
  int base = cs * 524288 + g * 32768 + (pt * 32 + tr * 2) * 64 + tc * 4;
  f32x4 o0, o1;
  #pragma unroll
  for (int j = 0; j < 4; ++j) { o0[j] = ctx[0][j]; o1[j] = ctx[1][j]; }
  *(f32x4*)&ctxp[base]      = o0;
  *(f32x4*)&ctxp[base + 64] = o1;
}

// ---------------------------------------------------------------------------
// Kernel 3: output GEMM; A-staging fuses 4-way c-split combine + expm1 + bf16
// unscramble; B-staging converts Wo fp32->bf16. Plain fp32 store to ao.
// ---------------------------------------------------------------------------
__global__ __launch_bounds__(256) void k_gemm1c(const float* __restrict__ ctxp,
    const float* __restrict__ Wo, float* __restrict__ ao)
{
  __shared__ unsigned short As[64][72];
  __shared__ unsigned short Bs[64][72];
  const int tid = threadIdx.x;
  const int r0 = blockIdx.y * 64, c0 = blockIdx.x * 64;
  const int w = tid >> 6, l = tid & 63;
  const int wr = (w >> 1) * 32, wc = (w & 1) * 32;
  const int srow = tid >> 3, sk8 = (tid & 7) * 8;
  f32x4 acc[2][2] = {};
  for (int kk = 0; kk < 512; kk += 64) {
    __syncthreads();
    #pragma unroll
    for (int q2 = 0; q2 < 2; ++q2) {
      int row = srow + q2 * 32;
      // A: combine ctxp partials for token row r0+row, dims kk+sk8..+7
      int r = r0 + row;
      int p = r >> 1, b2 = r & 1;
      int j0 = kk + sk8;
      int h2 = j0 >> 6, d0 = j0 & 63;
      const float* cp = ctxp + (b2 * 8 + h2) * 32768 + p * 64 + d0;
      f32x4 m0 = *(const f32x4*)cp;
      f32x4 m1 = *(const f32x4*)(cp + 4);
      #pragma unroll
      for (int cs = 1; cs < 4; ++cs) {
        f32x4 a0 = *(const f32x4*)(cp + cs * 524288);
        f32x4 a1 = *(const f32x4*)(cp + cs * 524288 + 4);
        #pragma unroll
        for (int e = 0; e < 4; ++e) {
          m0[e] = fmaxf(m0[e], a0[e]);
          m1[e] = fmaxf(m1[e], a1[e]);
        }
      }
      ushort4 lo, hi;
      lo.x = f2bf(expm1f(m0[0])); lo.y = f2bf(expm1f(m0[1]));
      lo.z = f2bf(expm1f(m0[2])); lo.w = f2bf(expm1f(m0[3]));
      hi.x = f2bf(expm1f(m1[0])); hi.y = f2bf(expm1f(m1[1]));
      hi.z = f2bf(expm1f(m1[2])); hi.w = f2bf(expm1f(m1[3]));
      *(ushort4*)&As[row][sk8] = lo;
      *(ushort4*)&As[row][sk8 + 4] = hi;
      // B: Wo fp32 -> bf16
      const float* bp = &Wo[(c0 + row) * 512 + kk + sk8];
      cvt8_store(&Bs[row][sk8], *(const float4*)bp, *(const float4*)(bp + 4));
    }
    __syncthreads();
    #pragma unroll
    for (int ks = 0; ks < 2; ++ks) {
      const int kc = ks * 32 + (l >> 4) * 8;
      bf16x8 a0 = *(const bf16x8*)&As[wr +      (l & 15)][kc];
      bf16x8 a1 = *(const bf16x8*)&As[wr + 16 + (l & 15)][kc];
      bf16x8 b0 = *(const bf16x8*)&Bs[wc +      (l & 15)][kc];
      bf16x8 b1 = *(const bf16x8*)&Bs[wc + 16 + (l & 15)][kc];
      acc[0][0] = __builtin_amdgcn_mfma_f32_16x16x32_bf16(a0, b0, acc[0][0], 0, 0, 0);
      acc[0][1] = __builtin_amdgcn_mfma_f32_16x16x32_bf16(a0, b1, acc[0][1], 0, 0, 0);
      acc[1][0] = __builtin_amdgcn_mfma_f32_16x16x32_bf16(a1, b0, acc[1][0], 0, 0, 0);
      acc[1][1] = __builtin_amdgcn_mfma_f32_16x16x32_bf16(a1, b1, acc[1][1], 0, 0, 0);
    }
  }
  #pragma unroll
  for (int i = 0; i < 2; ++i)
    #pragma unroll
    for (int j = 0; j < 2; ++j)
      #pragma unroll
      for (int r = 0; r < 4; ++r) {
        int row = r0 + wr + i * 16 + (l >> 4) * 4 + r;
        int col = c0 + wc + j * 16 + (l & 15);
        ao[row * 512 + col] = acc[i][j][r];
      }
}

// ---------------------------------------------------------------------------
// Kernel 4: residual + LayerNorm per row (D=512), one block per row
// ---------------------------------------------------------------------------
__global__ __launch_bounds__(256) void k_ln(const float* __restrict__ hin,
    const float* __restrict__ ao, const float* __restrict__ gamma,
    const float* __restrict__ beta, float* __restrict__ outp)
{
  const int r = blockIdx.x;
  const int tid = threadIdx.x;
  float2 hv = *(const float2*)&hin[r * 512 + tid * 2];
  float2 a2 = *(const float2*)&ao[r * 512 + tid * 2];
  float x0 = hv.x + a2.x, x1 = hv.y + a2.y;
  float sum = x0 + x1;
  float sq = x0 * x0 + x1 * x1;
  #pragma unroll
  for (int o = 32; o > 0; o >>= 1) {
    sum += __shfl_down(sum, o);
    sq  += __shfl_down(sq, o);
  }
  __shared__ float rs[8];
  const int lane = tid & 63, w = tid >> 6;
  if (lane == 0) { rs[w] = sum; rs[4 + w] = sq; }
  __syncthreads();
  float tot   = rs[0] + rs[1] + rs[2] + rs[3];
  float totsq = rs[4] + rs[5] + rs[6] + rs[7];
  float mu  = tot * (1.f / 512.f);
  float var = totsq * (1.f / 512.f) - mu * mu;
  float rstd = rsqrtf(fmaxf(var, 0.f) + 1e-5f);
  int c0 = tid * 2;
  outp[r * 512 + c0]     = (x0 - mu) * rstd * gamma[c0]     + beta[c0];
  outp[r * 512 + c0 + 1] = (x1 - mu) * rstd * gamma[c0 + 1] + beta[c0 + 1];
}

// ---------------------------------------------------------------------------
extern "C" void kernel_launch(void* const* d_in, const int* in_sizes, int n_in,
                              void* d_out, int out_size, void* d_ws, size_t ws_size,
                              hipStream_t stream) {
  const float* hin   = (const float*)d_in[0];
  const float* Wq    = (const float*)d_in[1];
  const float* Wkv   = (const float*)d_in[2];
  const float* Wqt   = (const float*)d_in[3];
  const float* Wkt   = (const float*)d_in[4];
  const float* Wvt   = (const float*)d_in[5];
  const float* lam   = (const float*)d_in[6];
  const float* Wo    = (const float*)d_in[7];
  const float* gamma = (const float*)d_in[8];
  const float* beta  = (const float*)d_in[9];
  char* wsb = (char*)d_ws;
  // byte layout: [0,6M) qkvbuf fp32 (dead after attn; ao overlays [0,2M))
  //              [6M,14M) ctxp fp32 (4 c-splits x 2MB)
  float* qkvbuf = (float*)wsb;
  float* ctxp   = (float*)(wsb + 6291456);
  float* ao     = (float*)wsb;
  float* out    = (float*)d_out;

  k_gemm0t<<<dim3(24, 16),    256, 0, stream>>>(hin, Wq, Wkv, lam, Wqt, Wkt, Wvt, qkvbuf);
  k_attn  <<<dim3(16, 16, 4), 256, 0, stream>>>(qkvbuf, ctxp);
  k_gemm1c<<<dim3(8, 16),     256, 0, stream>>>(ctxp, Wo, ao);
  k_ln    <<<dim3(1024),      256, 0, stream>>>(hin, ao, gamma, beta, out);
}

// Round 5
// 80.758 us; speedup vs baseline: 1.0385x; 1.0385x over previous
//
#include <hip/hip_runtime.h>
#include <cmath>

typedef __attribute__((ext_vector_type(8))) __bf16 bf16x8;
typedef __attribute__((ext_vector_type(4))) float f32x4;

namespace {
constexpr int GP = 512;
constexpr int WS_Q = 0;
constexpr int WS_K = 524288;
constexpr int WS_V = 1048576;
}

__device__ inline unsigned short f2bf(float x) {
  union { float f; unsigned u; } v; v.f = x;
  unsigned r = v.u + 0x7fff + ((v.u >> 16) & 1);   // RNE
  return (unsigned short)(r >> 16);
}

__device__ inline void cvt8_store(unsigned short* dst, float4 a, float4 b) {
  ushort4 lo, hi;
  lo.x = f2bf(a.x); lo.y = f2bf(a.y); lo.z = f2bf(a.z); lo.w = f2bf(a.w);
  hi.x = f2bf(b.x); hi.y = f2bf(b.y); hi.z = f2bf(b.z); hi.w = f2bf(b.w);
  *(ushort4*)dst = lo; *(ushort4*)(dst + 4) = hi;
}

// ---------------------------------------------------------------------------
// Kernel 1: QKV projection (bf16 MFMA) + log1p(relu)-lam + tropical linear
//           + scramble-write of q/k/v.  grid (24,16).
// ---------------------------------------------------------------------------
__global__ __launch_bounds__(256) void k_gemm0t(const float* __restrict__ h,
    const float* __restrict__ Wq, const float* __restrict__ Wkv,
    const float* __restrict__ lam, const float* __restrict__ Wqt,
    const float* __restrict__ Wkt, const float* __restrict__ Wvt,
    float* __restrict__ qkv)
{
  __shared__ unsigned short As[64][72];
  __shared__ unsigned short Bs[64][72];
  __shared__ float Wl[64][65];
  __shared__ float nl[64][68];
  const int tid = threadIdx.x;
  const int bx = blockIdx.x;
  const int r0 = blockIdx.y * 64, c0 = bx * 64;
  const int which = c0 >> 9;            // 0=q,1=k,2=v
  const int hh = bx & 7;                // head
  const float* Wt = (which == 0) ? Wqt : (which == 1) ? Wkt : Wvt;
  #pragma unroll
  for (int q = 0; q < 16; ++q) {
    int idx = q * 256 + tid;
    Wl[idx >> 6][idx & 63] = Wt[idx];
  }
  const int w = tid >> 6, l = tid & 63;
  const int wr = (w >> 1) * 32, wc = (w & 1) * 32;
  const int srow = tid >> 3, sk8 = (tid & 7) * 8;
  f32x4 acc[2][2] = {};
  for (int kk = 0; kk < 512; kk += 64) {
    __syncthreads();
    #pragma unroll
    for (int q2 = 0; q2 < 2; ++q2) {
      int row = srow + q2 * 32;
      const float* ap = &h[(r0 + row) * 512 + kk + sk8];
      cvt8_store(&As[row][sk8], *(const float4*)ap, *(const float4*)(ap + 4));
      int c = c0 + row;
      const float* wrp = (c < 512) ? (Wq + c * 512) : (Wkv + (c - 512) * 512);
      cvt8_store(&Bs[row][sk8], *(const float4*)&wrp[kk + sk8],
                 *(const float4*)&wrp[kk + sk8 + 4]);
    }
    __syncthreads();
    #pragma unroll
    for (int ks = 0; ks < 2; ++ks) {
      const int kc = ks * 32 + (l >> 4) * 8;
      bf16x8 a0 = *(const bf16x8*)&As[wr +      (l & 15)][kc];
      bf16x8 a1 = *(const bf16x8*)&As[wr + 16 + (l & 15)][kc];
      bf16x8 b0 = *(const bf16x8*)&Bs[wc +      (l & 15)][kc];
      bf16x8 b1 = *(const bf16x8*)&Bs[wc + 16 + (l & 15)][kc];
      acc[0][0] = __builtin_amdgcn_mfma_f32_16x16x32_bf16(a0, b0, acc[0][0], 0, 0, 0);
      acc[0][1] = __builtin_amdgcn_mfma_f32_16x16x32_bf16(a0, b1, acc[0][1], 0, 0, 0);
      acc[1][0] = __builtin_amdgcn_mfma_f32_16x16x32_bf16(a1, b0, acc[1][0], 0, 0, 0);
      acc[1][1] = __builtin_amdgcn_mfma_f32_16x16x32_bf16(a1, b1, acc[1][1], 0, 0, 0);
    }
  }
  #pragma unroll
  for (int i = 0; i < 2; ++i)
    #pragma unroll
    for (int j = 0; j < 2; ++j)
      #pragma unroll
      for (int r = 0; r < 4; ++r) {
        int rl = wr + i * 16 + (l >> 4) * 4 + r;
        int cl = wc + j * 16 + (l & 15);
        nl[rl][cl] = log1pf(fmaxf(acc[i][j][r], 0.f)) - lam[hh * 64 + cl];
      }
  __syncthreads();
  float wreg[64];
  #pragma unroll
  for (int i = 0; i < 64; ++i) wreg[i] = Wl[l][i];
  #pragma unroll 2
  for (int it = 0; it < 16; ++it) {
    int lr = w + it * 4;                 // wave-uniform row -> broadcast reads
    float m0 = -INFINITY, m1 = -INFINITY;
    #pragma unroll
    for (int i = 0; i < 64; i += 4) {
      f32x4 nv = *(const f32x4*)&nl[lr][i];
      float t0 = nv[0] + wreg[i],     t1 = nv[1] + wreg[i + 1];
      float t2 = nv[2] + wreg[i + 2], t3 = nv[3] + wreg[i + 3];
      m0 = fmaxf(fmaxf(m0, t0), t1);   // v_max3
      m1 = fmaxf(fmaxf(m1, t2), t3);
    }
    int r = r0 + lr;
    int s = r >> 1, bb = r & 1;
    int g = bb * 8 + (s >> 6);
    int p = ((s & 63) << 3) | hh;
    qkv[which * 524288 + ((g << 9) + p) * 64 + l] = fmaxf(m0, m1);
  }
}

// ---------------------------------------------------------------------------
// Kernel 2: tropical attention, 4x4 thread tiles, PT=64, 128 cols/block.
// phase1: score[p][c] = min_d(q-k) - max_d(q-k)  (rows 4tr+i, cols tc+16m)
// phase2: ctx[p][d]   = max_c(score + v[c][d])   (rows 4tr+i, dims 4tc+j)
// grid (8 pt, 16 g, 4 cs); fp32 partial ctx out.
// ---------------------------------------------------------------------------
__global__ __launch_bounds__(256) void k_attn(const float* __restrict__ qkv,
    float* __restrict__ ctxp)
{
  const int pt = blockIdx.x;        // 0..7  (64-row p-tile)
  const int g  = blockIdx.y;        // 0..15
  const int cs = blockIdx.z;        // 0..3  (128-col slice)
  const float* qb = qkv + WS_Q + g * GP * 64;
  const float* kb = qkv + WS_K + g * GP * 64;
  const float* vb = qkv + WS_V + g * GP * 64;
  __shared__ float qs[64][64];
  __shared__ float ks[64][64];
  __shared__ float vs[64][64];
  __shared__ float ss[64][68];
  const int tid = threadIdx.x;
  const int tr = tid >> 4, tc = tid & 15;
  // stage Q (XOR-swizzled 16B blocks)
  #pragma unroll
  for (int q4 = 0; q4 < 4; ++q4) {
    int row = tr + q4 * 16;
    *(f32x4*)&qs[row][(tc ^ (row & 7)) * 4] =
        *(const f32x4*)&qb[(pt * 64 + row) * 64 + tc * 4];
  }
  float ctx[4][4];
  #pragma unroll
  for (int i = 0; i < 4; ++i)
    #pragma unroll
    for (int j = 0; j < 4; ++j) ctx[i][j] = -INFINITY;

  const int xq0 = (4 * tr) & 7;     // row-swizzle bases for the 4 q rows
  for (int cc = 0; cc < 2; ++cc) {
    const int c0 = cs * 128 + cc * 64;
    __syncthreads();
    #pragma unroll
    for (int q4 = 0; q4 < 4; ++q4) {
      int row = tr + q4 * 16;
      int sb = (tc ^ (row & 7)) * 4;
      *(f32x4*)&ks[row][sb] = *(const f32x4*)&kb[(c0 + row) * 64 + tc * 4];
      *(f32x4*)&vs[row][sb] = *(const f32x4*)&vb[(c0 + row) * 64 + tc * 4];
    }
    __syncthreads();
    // ---- phase 1 ----
    float mx[4][4], mn[4][4];
    #pragma unroll
    for (int i = 0; i < 4; ++i)
      #pragma unroll
      for (int m = 0; m < 4; ++m) { mx[i][m] = -INFINITY; mn[i][m] = INFINITY; }
    #pragma unroll 4
    for (int b = 0; b < 16; ++b) {
      f32x4 qv[4], kv[4];
      #pragma unroll
      for (int i = 0; i < 4; ++i)
        qv[i] = *(const f32x4*)&qs[4 * tr + i][(b ^ ((xq0 + i) & 7)) * 4];
      const int kblk = (b ^ (tc & 7)) * 4;
      #pragma unroll
      for (int m = 0; m < 4; ++m)
        kv[m] = *(const f32x4*)&ks[tc + 16 * m][kblk];
      #pragma unroll
      for (int i = 0; i < 4; ++i)
        #pragma unroll
        for (int m = 0; m < 4; ++m) {
          float d0 = qv[i][0] - kv[m][0];
          float d1 = qv[i][1] - kv[m][1];
          float d2 = qv[i][2] - kv[m][2];
          float d3 = qv[i][3] - kv[m][3];
          mx[i][m] = fmaxf(fmaxf(mx[i][m], d0), d1);   // v_max3
          mn[i][m] = fminf(fminf(mn[i][m], d0), d1);   // v_min3
          mx[i][m] = fmaxf(fmaxf(mx[i][m], d2), d3);
          mn[i][m] = fminf(fminf(mn[i][m], d2), d3);
        }
    }
    #pragma unroll
    for (int i = 0; i < 4; ++i)
      #pragma unroll
      for (int m = 0; m < 4; ++m)
        ss[4 * tr + i][tc + 16 * m] = mn[i][m] - mx[i][m];
    __syncthreads();
    // ---- phase 2 ----
    #pragma unroll 4
    for (int cb = 0; cb < 16; ++cb) {
      f32x4 sv[4], vv[4];
      #pragma unroll
      for (int i = 0; i < 4; ++i)
        sv[i] = *(const f32x4*)&ss[4 * tr + i][cb * 4];
      #pragma unroll
      for (int e = 0; e < 4; ++e) {
        int c = cb * 4 + e;
        vv[e] = *(const f32x4*)&vs[c][(tc ^ (c & 7)) * 4];
      }
      #pragma unroll
      for (int i = 0; i < 4; ++i) {
        #pragma unroll
        for (int j = 0; j < 4; ++j)
          ctx[i][j] = fmaxf(fmaxf(ctx[i][j], sv[i][0] + vv[0][j]),
                            sv[i][1] + vv[1][j]);
        #pragma unroll
        for (int j = 0; j < 4; ++j)
          ctx[i][j] = fmaxf(fmaxf(ctx[i][j], sv[i][2] + vv[2][j]),
                            sv[i][3] + vv[3][j]);
      }
    }
  }
  int base = cs * 524288 + g * 32768 + (pt * 64 + 4 * tr) * 64 + tc * 4;
  #pragma unroll
  for (int i = 0; i < 4; ++i) {
    f32x4 o;
    #pragma unroll
    for (int j = 0; j < 4; ++j) o[j] = ctx[i][j];
    *(f32x4*)&ctxp[base + i * 64] = o;
  }
}

// ---------------------------------------------------------------------------
// Kernel 3: output GEMM; A-staging fuses c-split combine + expm1 + bf16;
// B-staging converts Wo fp32->bf16.
// ---------------------------------------------------------------------------
__global__ __launch_bounds__(256) void k_gemm1c(const float* __restrict__ ctxp,
    const float* __restrict__ Wo, float* __restrict__ ao)
{
  __shared__ unsigned short As[64][72];
  __shared__ unsigned short Bs[64][72];
  const int tid = threadIdx.x;
  const int r0 = blockIdx.y * 64, c0 = blockIdx.x * 64;
  const int w = tid >> 6, l = tid & 63;
  const int wr = (w >> 1) * 32, wc = (w & 1) * 32;
  const int srow = tid >> 3, sk8 = (tid & 7) * 8;
  f32x4 acc[2][2] = {};
  for (int kk = 0; kk < 512; kk += 64) {
    __syncthreads();
    #pragma unroll
    for (int q2 = 0; q2 < 2; ++q2) {
      int row = srow + q2 * 32;
      int r = r0 + row;
      int p = r >> 1, b2 = r & 1;
      int j0 = kk + sk8;
      int h2 = j0 >> 6, d0 = j0 & 63;
      const float* cp = ctxp + (b2 * 8 + h2) * 32768 + p * 64 + d0;
      f32x4 m0 = *(const f32x4*)cp;
      f32x4 m1 = *(const f32x4*)(cp + 4);
      #pragma unroll
      for (int cs = 1; cs < 4; ++cs) {
        f32x4 a0 = *(const f32x4*)(cp + cs * 524288);
        f32x4 a1 = *(const f32x4*)(cp + cs * 524288 + 4);
        #pragma unroll
        for (int e = 0; e < 4; ++e) {
          m0[e] = fmaxf(m0[e], a0[e]);
          m1[e] = fmaxf(m1[e], a1[e]);
        }
      }
      ushort4 lo, hi;
      lo.x = f2bf(expm1f(m0[0])); lo.y = f2bf(expm1f(m0[1]));
      lo.z = f2bf(expm1f(m0[2])); lo.w = f2bf(expm1f(m0[3]));
      hi.x = f2bf(expm1f(m1[0])); hi.y = f2bf(expm1f(m1[1]));
      hi.z = f2bf(expm1f(m1[2])); hi.w = f2bf(expm1f(m1[3]));
      *(ushort4*)&As[row][sk8] = lo;
      *(ushort4*)&As[row][sk8 + 4] = hi;
      const float* bp = &Wo[(c0 + row) * 512 + kk + sk8];
      cvt8_store(&Bs[row][sk8], *(const float4*)bp, *(const float4*)(bp + 4));
    }
    __syncthreads();
    #pragma unroll
    for (int ks = 0; ks < 2; ++ks) {
      const int kc = ks * 32 + (l >> 4) * 8;
      bf16x8 a0 = *(const bf16x8*)&As[wr +      (l & 15)][kc];
      bf16x8 a1 = *(const bf16x8*)&As[wr + 16 + (l & 15)][kc];
      bf16x8 b0 = *(const bf16x8*)&Bs[wc +      (l & 15)][kc];
      bf16x8 b1 = *(const bf16x8*)&Bs[wc + 16 + (l & 15)][kc];
      acc[0][0] = __builtin_amdgcn_mfma_f32_16x16x32_bf16(a0, b0, acc[0][0], 0, 0, 0);
      acc[0][1] = __builtin_amdgcn_mfma_f32_16x16x32_bf16(a0, b1, acc[0][1], 0, 0, 0);
      acc[1][0] = __builtin_amdgcn_mfma_f32_16x16x32_bf16(a1, b0, acc[1][0], 0, 0, 0);
      acc[1][1] = __builtin_amdgcn_mfma_f32_16x16x32_bf16(a1, b1, acc[1][1], 0, 0, 0);
    }
  }
  #pragma unroll
  for (int i = 0; i < 2; ++i)
    #pragma unroll
    for (int j = 0; j < 2; ++j)
      #pragma unroll
      for (int r = 0; r < 4; ++r) {
        int row = r0 + wr + i * 16 + (l >> 4) * 4 + r;
        int col = c0 + wc + j * 16 + (l & 15);
        ao[row * 512 + col] = acc[i][j][r];
      }
}

// ---------------------------------------------------------------------------
// Kernel 4: residual + LayerNorm, one WAVE per row (no LDS, no barriers)
// ---------------------------------------------------------------------------
__global__ __launch_bounds__(256) void k_ln(const float* __restrict__ hin,
    const float* __restrict__ ao, const float* __restrict__ gamma,
    const float* __restrict__ beta, float* __restrict__ outp)
{
  const int r = blockIdx.x * 4 + (threadIdx.x >> 6);
  const int lane = threadIdx.x & 63;
  const int c0 = lane * 8;
  f32x4 h0 = *(const f32x4*)&hin[r * 512 + c0];
  f32x4 h1 = *(const f32x4*)&hin[r * 512 + c0 + 4];
  f32x4 a0 = *(const f32x4*)&ao[r * 512 + c0];
  f32x4 a1 = *(const f32x4*)&ao[r * 512 + c0 + 4];
  float x[8];
  #pragma unroll
  for (int e = 0; e < 4; ++e) { x[e] = h0[e] + a0[e]; x[4 + e] = h1[e] + a1[e]; }
  float sum = 0.f, sq = 0.f;
  #pragma unroll
  for (int e = 0; e < 8; ++e) { sum += x[e]; sq += x[e] * x[e]; }
  #pragma unroll
  for (int o = 32; o > 0; o >>= 1) {
    sum += __shfl_xor(sum, o);
    sq  += __shfl_xor(sq, o);
  }
  float mu  = sum * (1.f / 512.f);
  float var = sq * (1.f / 512.f) - mu * mu;
  float rstd = rsqrtf(fmaxf(var, 0.f) + 1e-5f);
  f32x4 o0, o1;
  #pragma unroll
  for (int e = 0; e < 4; ++e) {
    o0[e] = (x[e]     - mu) * rstd * gamma[c0 + e]     + beta[c0 + e];
    o1[e] = (x[4 + e] - mu) * rstd * gamma[c0 + 4 + e] + beta[c0 + 4 + e];
  }
  *(f32x4*)&outp[r * 512 + c0]     = o0;
  *(f32x4*)&outp[r * 512 + c0 + 4] = o1;
}

// ---------------------------------------------------------------------------
extern "C" void kernel_launch(void* const* d_in, const int* in_sizes, int n_in,
                              void* d_out, int out_size, void* d_ws, size_t ws_size,
                              hipStream_t stream) {
  const float* hin   = (const float*)d_in[0];
  const float* Wq    = (const float*)d_in[1];
  const float* Wkv   = (const float*)d_in[2];
  const float* Wqt   = (const float*)d_in[3];
  const float* Wkt   = (const float*)d_in[4];
  const float* Wvt   = (const float*)d_in[5];
  const float* lam   = (const float*)d_in[6];
  const float* Wo    = (const float*)d_in[7];
  const float* gamma = (const float*)d_in[8];
  const float* beta  = (const float*)d_in[9];
  char* wsb = (char*)d_ws;
  // byte layout: [0,6M) qkvbuf fp32 (dead after attn; ao overlays [0,2M))
  //              [6M,14M) ctxp fp32 (4 c-splits x 2MB)
  float* qkvbuf = (float*)wsb;
  float* ctxp   = (float*)(wsb + 6291456);
  float* ao     = (float*)wsb;
  float* out    = (float*)d_out;

  k_gemm0t<<<dim3(24, 16),   256, 0, stream>>>(hin, Wq, Wkv, lam, Wqt, Wkt, Wvt, qkvbuf);
  k_attn  <<<dim3(8, 16, 4), 256, 0, stream>>>(qkvbuf, ctxp);
  k_gemm1c<<<dim3(8, 16),    256, 0, stream>>>(ctxp, Wo, ao);
  k_ln    <<<dim3(256),      256, 0, stream>>>(hin, ao, gamma, beta, out);
}